// Round 16
// baseline (152.357 us; speedup 1.0000x reference)
//
#include <hip/hip_runtime.h>
#include <stdint.h>

typedef unsigned int u32;
typedef unsigned long long u64;
typedef unsigned char u8;

#define BROWS 32
#define NPTS  262144           // 2^18 per row
#define LOG_NPTS 18
#define CB 256                 // coarse buckets per row
#define RCAP 1280              // fixed-region capacity per coarse bucket (mean 1024, +8 sigma)
#define ROWSTRIDE_FIX (CB * RCAP)   // 327680 record slots per row (fixed mode)
#define CCAP 1536              // staging cap per coarse bucket
#define FB2 1024               // fine cells per coarse bucket (mean 1)

// multisplit geometry: 1024 threads, 8 consecutive records/thread
#define MCH 8192
#define MWG 1024
// transpose multisplit geometry
#define TCH 8192
#define TWG 1024

// exact 22-bit grid: z0*2^22 is an exact f32 scaling (monotone in z0).
// cb = g22>>14 (8b), fb = (g22>>4)&1023 (10b), res = g22&15 (4b).
__device__ __forceinline__ u32 g22_of(float z0) {
    int b = (int)(z0 * 4194304.0f);
    return (u32)(b < 0 ? 0 : (b > 4194303 ? 4194303 : b));
}

// ---------- dense-mode pass 1: coarse histogram ----------
__global__ __launch_bounds__(256) void hist_kernel(const float* __restrict__ z,
                                                   u32* __restrict__ counts) {
    __shared__ u32 h[CB];
    for (int i = threadIdx.x; i < CB; i += 256) h[i] = 0;
    __syncthreads();
    int r = blockIdx.x >> 6;
    int c = blockIdx.x & 63;
    size_t base = ((size_t)r << LOG_NPTS) + (size_t)c * 4096;
    for (int k = 0; k < 16; ++k) {
        float z0 = z[(base + (size_t)(k * 256 + threadIdx.x)) * 3];
        atomicAdd(&h[g22_of(z0) >> 14], 1u);
    }
    __syncthreads();
    for (int i = threadIdx.x; i < CB; i += 256)
        if (h[i]) atomicAdd(&counts[r * CB + i], h[i]);
}

// ---------- dense-mode pass 2: scan counts -> offsets, gcur ----------
__global__ __launch_bounds__(256) void scan_dense(const u32* __restrict__ counts,
                                                  u32* __restrict__ offsets,
                                                  u32* __restrict__ gcur) {
    int r = blockIdx.x, t = threadIdx.x;
    __shared__ u32 sc[CB];
    u32 v = counts[r * CB + t];
    sc[t] = v;
    __syncthreads();
    u32 own = v;
    for (int off = 1; off < CB; off <<= 1) {
        u32 a = (t >= off) ? sc[t - off] : 0;
        __syncthreads();
        sc[t] += a;
        __syncthreads();
    }
    u32 ex = sc[t] - own;
    offsets[r * CB + t] = ex;
    gcur[r * CB + t] = ex;
}

// ---------- fixed-mode: post-scatter scan (cursors ARE counts; zero-based) ----------
__global__ __launch_bounds__(256) void scan_fixed(const u32* __restrict__ gcur,
                                                  u32* __restrict__ offsets,
                                                  u32* __restrict__ counts) {
    int r = blockIdx.x, t = threadIdx.x;
    __shared__ u32 sc[CB];
    u32 cnt = gcur[r * CB + t];
    if (cnt > RCAP) cnt = RCAP;
    counts[r * CB + t] = cnt;
    sc[t] = cnt;
    __syncthreads();
    u32 own = cnt;
    for (int off = 1; off < CB; off <<= 1) {
        u32 a = (t >= off) ? sc[t - off] : 0;
        __syncthreads();
        sc[t] += a;
        __syncthreads();
    }
    offsets[r * CB + t] = sc[t] - own;
}

// ---------- pass 3: multisplit scatter of 4B tags (res4<<28 | fb<<18 | idx) ----------
__global__ __launch_bounds__(MWG) void ms_scatter(const float* __restrict__ z,
                                                  u32* __restrict__ gcur,
                                                  u32* __restrict__ rec,
                                                  int fixedMode) {
    __shared__ u32 h[CB], sc[CB], gb[CB], wtot[4];
    __shared__ u32 reord[MCH];         // 32 KB
    __shared__ u8 rb8[MCH];            // 8 KB
    int t = threadIdx.x;
    int r = blockIdx.x >> 5;           // 32 chunks of 8192 per row
    int c = blockIdx.x & 31;
    if (t < CB) h[t] = 0;
    __syncthreads();

    // each thread: 8 consecutive points via 6 float4 loads
    u32 base_pt = (u32)(c * MCH + t * 8);
    const float4* zf4 = (const float4*)(z + ((size_t)r << LOG_NPTS) * 3 + (size_t)base_pt * 3);
    float4 f[6];
#pragma unroll
    for (int j = 0; j < 6; ++j) f[j] = zf4[j];
    const float* ff = (const float*)f;

    u32 mpk[8], mv[8];
#pragma unroll
    for (int k = 0; k < 8; ++k) {
        u32 g = g22_of(ff[3 * k]);
        u32 b = g >> 14;
        mv[k] = ((g & 15u) << 28) | (((g >> 4) & 1023u) << 18) | (base_pt + (u32)k);
        u32 arr = atomicAdd(&h[b], 1u);
        mpk[k] = (b << 16) | arr;
    }
    __syncthreads();
    // wave-shfl scan of 256 counts (waves 0-3)
    u32 scan_s = 0, scan_v = 0;
    int lane = t & 63, wv = t >> 6;
    if (t < CB) {
        scan_v = h[t];
        scan_s = scan_v;
        for (int off = 1; off < 64; off <<= 1) {
            u32 o = __shfl_up(scan_s, off, 64);
            if (lane >= off) scan_s += o;
        }
        if (lane == 63) wtot[wv] = scan_s;
    }
    __syncthreads();
    if (t < CB) {
        u32 wb = 0;
        if (wv > 0) wb += wtot[0];
        if (wv > 1) wb += wtot[1];
        if (wv > 2) wb += wtot[2];
        sc[t] = wb + scan_s - scan_v;
        gb[t] = atomicAdd(&gcur[r * CB + t], h[t]);
    }
    __syncthreads();
#pragma unroll
    for (int k = 0; k < 8; ++k) {
        u32 b = mpk[k] >> 16, arr = mpk[k] & 0xFFFFu;
        u32 p = sc[b] + arr;
        reord[p] = mv[k];
        rb8[p] = (u8)b;
    }
    __syncthreads();
    size_t rowrec = fixedMode ? (size_t)r * ROWSTRIDE_FIX : ((size_t)r << LOG_NPTS);
#pragma unroll
    for (int k = 0; k < 8; ++k) {
        u32 s = (u32)(k * MWG + t);
        u32 v = reord[s];
        u32 b = rb8[s];
        u32 local = gb[b] + (s - sc[b]);       // zero-based cursor position
        if (fixedMode) {
            if (local < (u32)RCAP)
                rec[rowrec + (size_t)b * RCAP + local] = v;
        } else {
            rec[rowrec + local] = v;           // gb absolute in dense mode
        }
    }
}

// ---------- pass 4: rank sort; res4 in LDS, lazy per-component z compare on ties ----------
__global__ __launch_bounds__(256) void fine_sort(const u32* __restrict__ rec,
                                                 const float* __restrict__ z,
                                                 const u32* __restrict__ offsets,
                                                 const u32* __restrict__ counts,
                                                 u32* __restrict__ tcur,
                                                 int* __restrict__ out_pa,
                                                 int fixedMode) {
    __shared__ u32 kv[CCAP];           // (res4<<18) | idx  (contested cells only)
    __shared__ u32 fh[FB2], fex[FB2], wtot[4];
    int t = threadIdx.x;
    int g = blockIdx.x;
    int r = g >> 8, cbk = g & 255;
    if (t == 0) tcur[g] = 0;           // pre-zero transpose cursors for trans_ms
    size_t rowrec = fixedMode ? (size_t)r * ROWSTRIDE_FIX : ((size_t)r << LOG_NPTS);
    u32 rdstart = fixedMode ? (u32)cbk * RCAP : offsets[g];
    u32 wrstart = offsets[g];
    u32 count = counts[g];
    u32 cap = fixedMode ? (u32)RCAP : (u32)CCAP;
    if (count > cap) count = cap;
    for (int i = t; i < FB2; i += 256) fh[i] = 0;
    __syncthreads();

    u32 rid[6], rres[6], rpk[6];
#pragma unroll
    for (int k = 0; k < 6; ++k) {
        u32 s = (u32)t + (u32)k * 256u;
        rpk[k] = 0xFFFFFFFFu;
        if (s < count) {
            u32 tag = rec[rowrec + rdstart + s];
            u32 fb = (tag >> 18) & 1023u;
            rid[k] = tag & 0x3FFFFu;
            rres[k] = tag >> 28;
            u32 arr = atomicAdd(&fh[fb], 1u);
            rpk[k] = (fb << 16) | arr;
        }
    }
    __syncthreads();
    // two-level scan of 1024 cell counts (4 per thread)
    {
        u32 v0 = fh[4 * t], v1 = fh[4 * t + 1], v2 = fh[4 * t + 2], v3 = fh[4 * t + 3];
        u32 tsum = v0 + v1 + v2 + v3;
        u32 s = tsum;
        int lane = t & 63, w = t >> 6;
        for (int off = 1; off < 64; off <<= 1) {
            u32 o = __shfl_up(s, off, 64);
            if (lane >= off) s += o;
        }
        if (lane == 63) wtot[w] = s;
        __syncthreads();
        u32 wbase = 0;
        if (w > 0) wbase += wtot[0];
        if (w > 1) wbase += wtot[1];
        if (w > 2) wbase += wtot[2];
        u32 ex = wbase + s - tsum;
        fex[4 * t] = ex;
        fex[4 * t + 1] = ex + v0;
        fex[4 * t + 2] = ex + v0 + v1;
        fex[4 * t + 3] = ex + v0 + v1 + v2;
    }
    __syncthreads();
#pragma unroll
    for (int k = 0; k < 6; ++k) {
        if (rpk[k] != 0xFFFFFFFFu) {
            u32 fb = rpk[k] >> 16, arr = rpk[k] & 0xFFFFu;
            if (fh[fb] > 1)                      // contested cells only
                kv[fex[fb] + arr] = (rres[k] << 18) | rid[k];
        }
    }
    __syncthreads();

    size_t orow = (size_t)r << LOG_NPTS;
    size_t zrow = ((size_t)r << LOG_NPTS) * 3;
#pragma unroll
    for (int k = 0; k < 6; ++k) {
        if (rpk[k] == 0xFFFFFFFFu) continue;
        u32 fb = rpk[k] >> 16;
        u32 cnt = fh[fb];
        u32 base = fex[fb];
        u32 pos = base;
        if (cnt > 1) {
            u32 rank = 0;
            u32 ares = rres[k], ai = rid[k];
            u32 a0 = 0, a1 = 0, a2 = 0;
            bool a0L = false, a1L = false, a2L = false;
            for (u32 j = 0; j < cnt; ++j) {
                u32 bv = kv[base + j];
                u32 bres = bv >> 18;
                if (bres < ares) { ++rank; continue; }
                if (bres > ares) continue;
                u32 bi = bv & 0x3FFFFu;
                if (bi == ai) continue;
                // res4 tie: lazy component-wise compare from global (rare)
                if (!a0L) { a0 = __float_as_uint(z[zrow + (size_t)ai * 3]); a0L = true; }
                u32 b0 = __float_as_uint(z[zrow + (size_t)bi * 3]);
                if (b0 < a0) { ++rank; continue; }
                if (b0 > a0) continue;
                if (!a1L) { a1 = __float_as_uint(z[zrow + (size_t)ai * 3 + 1]); a1L = true; }
                u32 b1 = __float_as_uint(z[zrow + (size_t)bi * 3 + 1]);
                if (b1 < a1) { ++rank; continue; }
                if (b1 > a1) continue;
                if (!a2L) { a2 = __float_as_uint(z[zrow + (size_t)ai * 3 + 2]); a2L = true; }
                u32 b2 = __float_as_uint(z[zrow + (size_t)bi * 3 + 2]);
                rank += (b2 < a2) || (b2 == a2 && bi < ai);
            }
            pos = base + rank;
        }
        out_pa[orow + wrstart + pos] = (int)rid[k];
    }
}

// ---------- pass 5: multisplit-transpose of the permutation (LDS reorder) ----------
__global__ __launch_bounds__(TWG) void trans_ms(const int* __restrict__ out_pa,
                                                u32* __restrict__ tcur,
                                                u32* __restrict__ pairs) {
    __shared__ u32 h[CB], sc[CB], gb[CB], wtot[4];
    __shared__ u32 reord[TCH];
    __shared__ u8 rb8[TCH];
    int t = threadIdx.x;
    int r = blockIdx.x >> 5;           // 32 chunks of 8192 per row
    int c = blockIdx.x & 31;
    if (t < CB) h[t] = 0;
    __syncthreads();
    u32 mpk[8], mv[8];
#pragma unroll
    for (int k = 0; k < 8; ++k) {
        u32 p = (u32)(c * TCH + k * TWG + t);
        u32 si = (u32)out_pa[((size_t)r << LOG_NPTS) + p];
        u32 b = si >> 10;
        mv[k] = ((si & 1023u) << 18) | p;
        u32 arr = atomicAdd(&h[b], 1u);
        mpk[k] = (b << 16) | arr;
    }
    __syncthreads();
    u32 scan_s = 0, scan_v = 0;
    int lane = t & 63, wv = t >> 6;
    if (t < CB) {
        scan_v = h[t];
        scan_s = scan_v;
        for (int off = 1; off < 64; off <<= 1) {
            u32 o = __shfl_up(scan_s, off, 64);
            if (lane >= off) scan_s += o;
        }
        if (lane == 63) wtot[wv] = scan_s;
    }
    __syncthreads();
    if (t < CB) {
        u32 wbase = 0;
        if (wv > 0) wbase += wtot[0];
        if (wv > 1) wbase += wtot[1];
        if (wv > 2) wbase += wtot[2];
        sc[t] = wbase + scan_s - scan_v;
        gb[t] = atomicAdd(&tcur[r * CB + t], h[t]);
    }
    __syncthreads();
#pragma unroll
    for (int k = 0; k < 8; ++k) {
        u32 b = mpk[k] >> 16, arr = mpk[k] & 0xFFFFu;
        u32 p = sc[b] + arr;
        reord[p] = mv[k];
        rb8[p] = (u8)b;
    }
    __syncthreads();
#pragma unroll
    for (int k = 0; k < 8; ++k) {
        u32 s = (u32)(k * TWG + t);
        u32 v = reord[s];
        u32 b = rb8[s];
        u32 local = s - sc[b];
        pairs[((size_t)r << LOG_NPTS) + (size_t)b * 1024 + gb[b] + local] = v;
    }
}

// ---------- pass 6: per-bucket reorder, coalesced out_re write ----------
__global__ __launch_bounds__(256) void trans_write(const u32* __restrict__ pairs,
                                                   int* __restrict__ out_re) {
    __shared__ u32 buf[1024];
    int g = blockIdx.x;
    int r = g >> 8, b = g & 255;
    size_t base = ((size_t)r << LOG_NPTS) + (size_t)b * 1024;
#pragma unroll
    for (int k = 0; k < 4; ++k) {
        u32 v = pairs[base + (size_t)(k * 256 + threadIdx.x)];
        buf[v >> 18] = v & 0x3FFFFu;
    }
    __syncthreads();
#pragma unroll
    for (int k = 0; k < 4; ++k) {
        int j = k * 256 + threadIdx.x;
        out_re[base + (size_t)j] = (int)buf[j];
    }
}

extern "C" void kernel_launch(void* const* d_in, const int* in_sizes, int n_in,
                              void* d_out, int out_size, void* d_ws, size_t ws_size,
                              hipStream_t stream) {
    const float* z = (const float*)d_in[0];
    int* out_pa = (int*)d_out;
    int* out_re = out_pa + (size_t)BROWS * NPTS;

    char* ws = (char*)d_ws;
    u32* counts  = (u32*)(ws);                 // 32 KB
    u32* offsets = (u32*)(ws + (64u << 10));   // 32 KB
    u32* gcur    = (u32*)(ws + (128u << 10));  // 32 KB
    u32* tcur    = (u32*)(ws + (160u << 10));  // 32 KB
    u32* rec     = (u32*)(ws + (1u << 20));    // 40 MiB (fixed) / 32 MiB (dense)
    u32* pairs   = (u32*)(ws + (1u << 20) + (48ull << 20));  // 32 MiB

    // fixed-region mode needs 1MiB + 48MiB + 32MiB = 81 MiB
    size_t need = (1ull << 20) + (48ull << 20) + (32ull << 20);
    int fixedMode = (ws_size >= need) ? 1 : 0;

    if (fixedMode) {
        hipMemsetAsync(gcur, 0, (size_t)BROWS * CB * sizeof(u32), stream);
        ms_scatter<<<BROWS * 32, MWG, 0, stream>>>(z, gcur, rec, 1);
        scan_fixed<<<BROWS, 256, 0, stream>>>(gcur, offsets, counts);
        fine_sort<<<BROWS * CB, 256, 0, stream>>>(rec, z, offsets, counts,
                                                  tcur, out_pa, 1);
    } else {
        hipMemsetAsync(counts, 0, (size_t)BROWS * CB * sizeof(u32), stream);
        hist_kernel<<<BROWS * 64, 256, 0, stream>>>(z, counts);
        scan_dense<<<BROWS, 256, 0, stream>>>(counts, offsets, gcur);
        ms_scatter<<<BROWS * 32, MWG, 0, stream>>>(z, gcur, rec, 0);
        fine_sort<<<BROWS * CB, 256, 0, stream>>>(rec, z, offsets, counts,
                                                  tcur, out_pa, 0);
    }
    trans_ms<<<BROWS * 32, TWG, 0, stream>>>(out_pa, tcur, pairs);
    trans_write<<<BROWS * CB, 256, 0, stream>>>(pairs, out_re);
}

// Round 17
// 132.088 us; speedup vs baseline: 1.1535x; 1.1535x over previous
//
#include <hip/hip_runtime.h>
#include <stdint.h>

typedef unsigned int u32;
typedef unsigned long long u64;
typedef unsigned char u8;

#define BROWS 32
#define NPTS  262144           // 2^18 per row
#define LOG_NPTS 18
#define CB 256                 // coarse buckets per row
#define RCAP 1280              // fixed-region capacity per coarse bucket (mean 1024, +8 sigma)
#define ROWSTRIDE_FIX (CB * RCAP)   // 327680 record slots per row (fixed mode)
#define CCAP 1536              // staging cap per coarse bucket
#define FB2 1024               // fine cells per coarse bucket (mean 1)

// multisplit geometry: 1024 threads, 8 consecutive records/thread
#define MCH 8192
#define MWG 1024
// transpose multisplit geometry
#define TCH 8192
#define TWG 1024

// exact 22-bit grid: z0*2^22 is an exact f32 scaling (monotone in z0).
// cb = g22>>14 (8b), fb = (g22>>4)&1023 (10b), res = g22&15 (4b).
__device__ __forceinline__ u32 g22_of(float z0) {
    int b = (int)(z0 * 4194304.0f);
    return (u32)(b < 0 ? 0 : (b > 4194303 ? 4194303 : b));
}

// ---------- dense-mode pass 1: coarse histogram ----------
__global__ __launch_bounds__(256) void hist_kernel(const float* __restrict__ z,
                                                   u32* __restrict__ counts) {
    __shared__ u32 h[CB];
    for (int i = threadIdx.x; i < CB; i += 256) h[i] = 0;
    __syncthreads();
    int r = blockIdx.x >> 6;
    int c = blockIdx.x & 63;
    size_t base = ((size_t)r << LOG_NPTS) + (size_t)c * 4096;
    for (int k = 0; k < 16; ++k) {
        float z0 = z[(base + (size_t)(k * 256 + threadIdx.x)) * 3];
        atomicAdd(&h[g22_of(z0) >> 14], 1u);
    }
    __syncthreads();
    for (int i = threadIdx.x; i < CB; i += 256)
        if (h[i]) atomicAdd(&counts[r * CB + i], h[i]);
}

// ---------- dense-mode pass 2: scan counts -> offsets, gcur ----------
__global__ __launch_bounds__(256) void scan_dense(const u32* __restrict__ counts,
                                                  u32* __restrict__ offsets,
                                                  u32* __restrict__ gcur) {
    int r = blockIdx.x, t = threadIdx.x;
    __shared__ u32 sc[CB];
    u32 v = counts[r * CB + t];
    sc[t] = v;
    __syncthreads();
    u32 own = v;
    for (int off = 1; off < CB; off <<= 1) {
        u32 a = (t >= off) ? sc[t - off] : 0;
        __syncthreads();
        sc[t] += a;
        __syncthreads();
    }
    u32 ex = sc[t] - own;
    offsets[r * CB + t] = ex;
    gcur[r * CB + t] = ex;
}

// ---------- fixed-mode: post-scatter scan (cursors ARE counts; zero-based) ----------
__global__ __launch_bounds__(256) void scan_fixed(const u32* __restrict__ gcur,
                                                  u32* __restrict__ offsets,
                                                  u32* __restrict__ counts) {
    int r = blockIdx.x, t = threadIdx.x;
    __shared__ u32 sc[CB];
    u32 cnt = gcur[r * CB + t];
    if (cnt > RCAP) cnt = RCAP;
    counts[r * CB + t] = cnt;
    sc[t] = cnt;
    __syncthreads();
    u32 own = cnt;
    for (int off = 1; off < CB; off <<= 1) {
        u32 a = (t >= off) ? sc[t - off] : 0;
        __syncthreads();
        sc[t] += a;
        __syncthreads();
    }
    offsets[r * CB + t] = sc[t] - own;
}

// ---------- pass 3: multisplit scatter of 4B tags (res4<<28 | fb<<18 | idx) ----------
__global__ __launch_bounds__(MWG) void ms_scatter(const float* __restrict__ z,
                                                  u32* __restrict__ gcur,
                                                  u32* __restrict__ rec,
                                                  int fixedMode) {
    __shared__ u32 h[CB], sc[CB], gb[CB], wtot[4];
    __shared__ u32 reord[MCH];         // 32 KB
    __shared__ u8 rb8[MCH];            // 8 KB
    int t = threadIdx.x;
    int r = blockIdx.x >> 5;           // 32 chunks of 8192 per row
    int c = blockIdx.x & 31;
    if (t < CB) h[t] = 0;
    __syncthreads();

    // each thread: 8 consecutive points via 6 float4 loads
    u32 base_pt = (u32)(c * MCH + t * 8);
    const float4* zf4 = (const float4*)(z + ((size_t)r << LOG_NPTS) * 3 + (size_t)base_pt * 3);
    float4 f[6];
#pragma unroll
    for (int j = 0; j < 6; ++j) f[j] = zf4[j];
    const float* ff = (const float*)f;

    u32 mpk[8], mv[8];
#pragma unroll
    for (int k = 0; k < 8; ++k) {
        u32 g = g22_of(ff[3 * k]);
        u32 b = g >> 14;
        mv[k] = ((g & 15u) << 28) | (((g >> 4) & 1023u) << 18) | (base_pt + (u32)k);
        u32 arr = atomicAdd(&h[b], 1u);
        mpk[k] = (b << 16) | arr;
    }
    __syncthreads();
    // wave-shfl scan of 256 counts (waves 0-3)
    u32 scan_s = 0, scan_v = 0;
    int lane = t & 63, wv = t >> 6;
    if (t < CB) {
        scan_v = h[t];
        scan_s = scan_v;
        for (int off = 1; off < 64; off <<= 1) {
            u32 o = __shfl_up(scan_s, off, 64);
            if (lane >= off) scan_s += o;
        }
        if (lane == 63) wtot[wv] = scan_s;
    }
    __syncthreads();
    if (t < CB) {
        u32 wb = 0;
        if (wv > 0) wb += wtot[0];
        if (wv > 1) wb += wtot[1];
        if (wv > 2) wb += wtot[2];
        sc[t] = wb + scan_s - scan_v;
        gb[t] = atomicAdd(&gcur[r * CB + t], h[t]);
    }
    __syncthreads();
#pragma unroll
    for (int k = 0; k < 8; ++k) {
        u32 b = mpk[k] >> 16, arr = mpk[k] & 0xFFFFu;
        u32 p = sc[b] + arr;
        reord[p] = mv[k];
        rb8[p] = (u8)b;
    }
    __syncthreads();
    size_t rowrec = fixedMode ? (size_t)r * ROWSTRIDE_FIX : ((size_t)r << LOG_NPTS);
#pragma unroll
    for (int k = 0; k < 8; ++k) {
        u32 s = (u32)(k * MWG + t);
        u32 v = reord[s];
        u32 b = rb8[s];
        u32 local = gb[b] + (s - sc[b]);       // zero-based cursor position
        if (fixedMode) {
            if (local < (u32)RCAP)
                rec[rowrec + (size_t)b * RCAP + local] = v;
        } else {
            rec[rowrec + local] = v;           // gb absolute in dense mode
        }
    }
}

// ---------- pass 4: rank sort; res4 in LDS, full-z gather only on res4 ties ----------
__global__ __launch_bounds__(256) void fine_sort(const u32* __restrict__ rec,
                                                 const float* __restrict__ z,
                                                 const u32* __restrict__ offsets,
                                                 const u32* __restrict__ counts,
                                                 u32* __restrict__ tcur,
                                                 int* __restrict__ out_pa,
                                                 int fixedMode) {
    __shared__ u32 kv[CCAP];           // (res4<<18) | idx  (contested cells only)
    __shared__ u32 fh[FB2], fex[FB2], wtot[4];
    int t = threadIdx.x;
    int g = blockIdx.x;
    int r = g >> 8, cbk = g & 255;
    if (t == 0) tcur[g] = 0;           // pre-zero transpose cursors for trans_ms
    size_t rowrec = fixedMode ? (size_t)r * ROWSTRIDE_FIX : ((size_t)r << LOG_NPTS);
    u32 rdstart = fixedMode ? (u32)cbk * RCAP : offsets[g];
    u32 wrstart = offsets[g];
    u32 count = counts[g];
    u32 cap = fixedMode ? (u32)RCAP : (u32)CCAP;
    if (count > cap) count = cap;
    for (int i = t; i < FB2; i += 256) fh[i] = 0;
    __syncthreads();

    u32 rid[6], rres[6], rpk[6];
#pragma unroll
    for (int k = 0; k < 6; ++k) {
        u32 s = (u32)t + (u32)k * 256u;
        rpk[k] = 0xFFFFFFFFu;
        if (s < count) {
            u32 tag = rec[rowrec + rdstart + s];
            u32 fb = (tag >> 18) & 1023u;
            rid[k] = tag & 0x3FFFFu;
            rres[k] = tag >> 28;
            u32 arr = atomicAdd(&fh[fb], 1u);
            rpk[k] = (fb << 16) | arr;
        }
    }
    __syncthreads();
    // two-level scan of 1024 cell counts (4 per thread)
    {
        u32 v0 = fh[4 * t], v1 = fh[4 * t + 1], v2 = fh[4 * t + 2], v3 = fh[4 * t + 3];
        u32 tsum = v0 + v1 + v2 + v3;
        u32 s = tsum;
        int lane = t & 63, w = t >> 6;
        for (int off = 1; off < 64; off <<= 1) {
            u32 o = __shfl_up(s, off, 64);
            if (lane >= off) s += o;
        }
        if (lane == 63) wtot[w] = s;
        __syncthreads();
        u32 wbase = 0;
        if (w > 0) wbase += wtot[0];
        if (w > 1) wbase += wtot[1];
        if (w > 2) wbase += wtot[2];
        u32 ex = wbase + s - tsum;
        fex[4 * t] = ex;
        fex[4 * t + 1] = ex + v0;
        fex[4 * t + 2] = ex + v0 + v1;
        fex[4 * t + 3] = ex + v0 + v1 + v2;
    }
    __syncthreads();
#pragma unroll
    for (int k = 0; k < 6; ++k) {
        if (rpk[k] != 0xFFFFFFFFu) {
            u32 fb = rpk[k] >> 16, arr = rpk[k] & 0xFFFFu;
            if (fh[fb] > 1)                      // contested cells only
                kv[fex[fb] + arr] = (rres[k] << 18) | rid[k];
        }
    }
    __syncthreads();

    size_t orow = (size_t)r << LOG_NPTS;
    size_t zrow = ((size_t)r << LOG_NPTS) * 3;
#pragma unroll
    for (int k = 0; k < 6; ++k) {
        if (rpk[k] == 0xFFFFFFFFu) continue;
        u32 fb = rpk[k] >> 16;
        u32 cnt = fh[fb];
        u32 base = fex[fb];
        u32 pos = base;
        if (cnt > 1) {
            u32 rank = 0;
            u32 ares = rres[k], ai = rid[k];
            u32 a0 = 0, a1 = 0, a2 = 0;
            bool aLoaded = false;
            for (u32 j = 0; j < cnt; ++j) {
                u32 bv = kv[base + j];
                u32 bres = bv >> 18;
                if (bres < ares) { ++rank; continue; }
                if (bres == ares) {
                    u32 bi = bv & 0x3FFFFu;
                    if (bi == ai) continue;
                    // res4 tie: full lexicographic compare from global (rare ~1.6%)
                    if (!aLoaded) {
                        a0 = __float_as_uint(z[zrow + (size_t)ai * 3]);
                        a1 = __float_as_uint(z[zrow + (size_t)ai * 3 + 1]);
                        a2 = __float_as_uint(z[zrow + (size_t)ai * 3 + 2]);
                        aLoaded = true;
                    }
                    u32 b0 = __float_as_uint(z[zrow + (size_t)bi * 3]);
                    if (b0 < a0) { ++rank; continue; }
                    if (b0 > a0) continue;
                    u32 b1 = __float_as_uint(z[zrow + (size_t)bi * 3 + 1]);
                    if (b1 < a1) { ++rank; continue; }
                    if (b1 > a1) continue;
                    u32 b2 = __float_as_uint(z[zrow + (size_t)bi * 3 + 2]);
                    rank += (b2 < a2) || (b2 == a2 && bi < ai);
                }
            }
            pos = base + rank;
        }
        out_pa[orow + wrstart + pos] = (int)rid[k];
    }
}

// ---------- pass 5: multisplit-transpose of the permutation (LDS reorder) ----------
__global__ __launch_bounds__(TWG) void trans_ms(const int* __restrict__ out_pa,
                                                u32* __restrict__ tcur,
                                                u32* __restrict__ pairs) {
    __shared__ u32 h[CB], sc[CB], gb[CB], wtot[4];
    __shared__ u32 reord[TCH];
    __shared__ u8 rb8[TCH];
    int t = threadIdx.x;
    int r = blockIdx.x >> 5;           // 32 chunks of 8192 per row
    int c = blockIdx.x & 31;
    if (t < CB) h[t] = 0;
    __syncthreads();
    u32 mpk[8], mv[8];
#pragma unroll
    for (int k = 0; k < 8; ++k) {
        u32 p = (u32)(c * TCH + k * TWG + t);
        u32 si = (u32)out_pa[((size_t)r << LOG_NPTS) + p];
        u32 b = si >> 10;
        mv[k] = ((si & 1023u) << 18) | p;
        u32 arr = atomicAdd(&h[b], 1u);
        mpk[k] = (b << 16) | arr;
    }
    __syncthreads();
    u32 scan_s = 0, scan_v = 0;
    int lane = t & 63, wv = t >> 6;
    if (t < CB) {
        scan_v = h[t];
        scan_s = scan_v;
        for (int off = 1; off < 64; off <<= 1) {
            u32 o = __shfl_up(scan_s, off, 64);
            if (lane >= off) scan_s += o;
        }
        if (lane == 63) wtot[wv] = scan_s;
    }
    __syncthreads();
    if (t < CB) {
        u32 wbase = 0;
        if (wv > 0) wbase += wtot[0];
        if (wv > 1) wbase += wtot[1];
        if (wv > 2) wbase += wtot[2];
        sc[t] = wbase + scan_s - scan_v;
        gb[t] = atomicAdd(&tcur[r * CB + t], h[t]);
    }
    __syncthreads();
#pragma unroll
    for (int k = 0; k < 8; ++k) {
        u32 b = mpk[k] >> 16, arr = mpk[k] & 0xFFFFu;
        u32 p = sc[b] + arr;
        reord[p] = mv[k];
        rb8[p] = (u8)b;
    }
    __syncthreads();
#pragma unroll
    for (int k = 0; k < 8; ++k) {
        u32 s = (u32)(k * TWG + t);
        u32 v = reord[s];
        u32 b = rb8[s];
        u32 local = s - sc[b];
        pairs[((size_t)r << LOG_NPTS) + (size_t)b * 1024 + gb[b] + local] = v;
    }
}

// ---------- pass 6: per-bucket reorder, coalesced out_re write ----------
__global__ __launch_bounds__(256) void trans_write(const u32* __restrict__ pairs,
                                                   int* __restrict__ out_re) {
    __shared__ u32 buf[1024];
    int g = blockIdx.x;
    int r = g >> 8, b = g & 255;
    size_t base = ((size_t)r << LOG_NPTS) + (size_t)b * 1024;
#pragma unroll
    for (int k = 0; k < 4; ++k) {
        u32 v = pairs[base + (size_t)(k * 256 + threadIdx.x)];
        buf[v >> 18] = v & 0x3FFFFu;
    }
    __syncthreads();
#pragma unroll
    for (int k = 0; k < 4; ++k) {
        int j = k * 256 + threadIdx.x;
        out_re[base + (size_t)j] = (int)buf[j];
    }
}

extern "C" void kernel_launch(void* const* d_in, const int* in_sizes, int n_in,
                              void* d_out, int out_size, void* d_ws, size_t ws_size,
                              hipStream_t stream) {
    const float* z = (const float*)d_in[0];
    int* out_pa = (int*)d_out;
    int* out_re = out_pa + (size_t)BROWS * NPTS;

    char* ws = (char*)d_ws;
    u32* counts  = (u32*)(ws);                 // 32 KB
    u32* offsets = (u32*)(ws + (64u << 10));   // 32 KB
    u32* gcur    = (u32*)(ws + (128u << 10));  // 32 KB
    u32* tcur    = (u32*)(ws + (160u << 10));  // 32 KB
    u32* rec     = (u32*)(ws + (1u << 20));    // 40 MiB (fixed) / 32 MiB (dense)
    u32* pairs   = (u32*)(ws + (1u << 20) + (48ull << 20));  // 32 MiB

    // fixed-region mode needs 1MiB + 48MiB + 32MiB = 81 MiB
    size_t need = (1ull << 20) + (48ull << 20) + (32ull << 20);
    int fixedMode = (ws_size >= need) ? 1 : 0;

    if (fixedMode) {
        hipMemsetAsync(gcur, 0, (size_t)BROWS * CB * sizeof(u32), stream);
        ms_scatter<<<BROWS * 32, MWG, 0, stream>>>(z, gcur, rec, 1);
        scan_fixed<<<BROWS, 256, 0, stream>>>(gcur, offsets, counts);
        fine_sort<<<BROWS * CB, 256, 0, stream>>>(rec, z, offsets, counts,
                                                  tcur, out_pa, 1);
    } else {
        hipMemsetAsync(counts, 0, (size_t)BROWS * CB * sizeof(u32), stream);
        hist_kernel<<<BROWS * 64, 256, 0, stream>>>(z, counts);
        scan_dense<<<BROWS, 256, 0, stream>>>(counts, offsets, gcur);
        ms_scatter<<<BROWS * 32, MWG, 0, stream>>>(z, gcur, rec, 0);
        fine_sort<<<BROWS * CB, 256, 0, stream>>>(rec, z, offsets, counts,
                                                  tcur, out_pa, 0);
    }
    trans_ms<<<BROWS * 32, TWG, 0, stream>>>(out_pa, tcur, pairs);
    trans_write<<<BROWS * CB, 256, 0, stream>>>(pairs, out_re);
}